// Round 7
// baseline (152.446 us; speedup 1.0000x reference)
//
#include <hip/hip_runtime.h>
#include <hip/hip_fp16.h>
#include <stdint.h>

// Problem constants (hardcoded per reference)
#define NROWS 131072   // B*L
#define DIM   256      // D
#define HDK   128      // H*DK
#define BM    16       // rows per tile
#define TPB   4        // tiles per block
#define NBLK  (NROWS / BM / TPB)   // 2048 blocks

typedef _Float16 f16x8 __attribute__((ext_vector_type(8)));
typedef float    f32x4 __attribute__((ext_vector_type(4)));

// ---------------------------------------------------------------------------
// Pack W_q, W_k, W_v (256x128) and W_o (128x256) into fragment-linear fp16.
// Proj p at p*32768: frag idx = ((nt*8 + ks)*64 + lane)*8 + j,
//   value = W[ks*32 + (lane>>4)*8 + j][nt*16 + (lane&15)]   (nt = head)
// W_o at 98304: frag idx = ((nto*4 + ks)*64 + lane)*8 + j, COLUMN PERMUTE:
//   actual col n = (nto>>1)*32 + (lane&15)*2 + (nto&1)
// so wave w (tiles nto=2w,2w+1) gives each lane 2 consecutive output columns.
// ---------------------------------------------------------------------------
__global__ void pack_w(const float* __restrict__ Wq, const float* __restrict__ Wk,
                       const float* __restrict__ Wv, const float* __restrict__ Wo,
                       _Float16* __restrict__ wt) {
  int t = blockIdx.x * 256 + threadIdx.x;   // 0 .. 131071
  int seg = t >> 15;                        // 0..3
  int i = t & 32767;
  int j = i & 7;
  int l = (i >> 3) & 63;
  int rest = i >> 9;                        // nt*KS + ks
  const float* W;
  int N, k, n;
  if (seg < 3) {
    W = (seg == 0) ? Wq : ((seg == 1) ? Wk : Wv);
    N = HDK;
    int ks = rest & 7, nt = rest >> 3;
    k = ks * 32 + ((l >> 4) << 3) + j;      // 0..255
    n = nt * 16 + (l & 15);                 // 0..127
  } else {
    W = Wo;
    N = DIM;
    int ks = rest & 3, nt = rest >> 2;      // nt = nto in 0..15
    k = ks * 32 + ((l >> 4) << 3) + j;      // 0..127
    n = ((nt >> 1) << 5) + ((l & 15) << 1) + (nt & 1);  // permuted column
  }
  wt[t] = (_Float16)W[k * N + n];
}

// ---------------------------------------------------------------------------
// v7 = v6 (persistent-weight waves, swapped-operand proj -> register-axis
// softmax, register-prefetched double-buffered staging) plus:
//  (a) finale Q,V float2 pairs prefetched at the TOP of each tile iteration
//      (ride out proj+softmax+barrier+W_o ~1500 cy; finale is pure VALU+store)
//  (b) TPB 8->4: grid 2048 blocks, halves the residency tail.
// ---------------------------------------------------------------------------
__launch_bounds__(512, 2)
__global__ void uan_main(const float* __restrict__ Qg, const float* __restrict__ Kg,
                         const float* __restrict__ Vg, const _Float16* __restrict__ wt,
                         const float* __restrict__ Wl, const float* __restrict__ blv,
                         const float* __restrict__ Wsv, const float* __restrict__ bsv,
                         float* __restrict__ outg) {
  __shared__ __align__(16) _Float16 sF0[1536 * 8];   // 24576 B
  __shared__ __align__(16) _Float16 sF1[1536 * 8];   // 24576 B
  __shared__ __align__(16) _Float16 sVAf[256 * 8];   //  4096 B

  const int tid  = threadIdx.x;
  const int lane = tid & 63;
  const int w    = tid >> 6;        // wave 0..7 == head
  const int c16  = lane & 15;
  const int kg   = lane >> 4;

  // ---- held B-fragments (loaded once per block life) ----
  f16x8 bwp[24];   // proj: [p*8 + ks], head w
#pragma unroll
  for (int p = 0; p < 3; ++p)
#pragma unroll
    for (int ks = 0; ks < 8; ++ks)
      bwp[p * 8 + ks] = *(const f16x8*)(wt + p * 32768 +
                         (size_t)(((w * 8 + ks) * 64) + lane) * 8);
  f16x8 bo[8];     // W_o: [nt*4 + ks], tiles nto = 2w, 2w+1
#pragma unroll
  for (int nt = 0; nt < 2; ++nt)
#pragma unroll
    for (int ks = 0; ks < 4; ++ks)
      bo[nt * 4 + ks] = *(const f16x8*)(wt + 98304 +
                         (size_t)((((2 * w + nt) * 4 + ks) * 64) + lane) * 8);

  const float bl0 = blv[0], bl1 = blv[1], bs0 = bsv[0];
  // per-register softmax constants: hd = kg*4 + q
  float wl0q[4], wl1q[4], wsq[4];
#pragma unroll
  for (int q = 0; q < 4; ++q) {
    wl0q[q] = Wl[kg * 4 + q];
    wl1q[q] = Wl[16 + kg * 4 + q];
    wsq[q]  = Wsv[kg * 4 + q];
  }

  // staging: thread stages row (row0+c16)'s cols [w*32+kg*8, +8) of each plane
  const size_t soff  = (size_t)c16 * DIM + w * 32 + kg * 8;
  const size_t sfrag = (size_t)(w * 64 + lane) * 8;   // + p*4096 per plane

  float4 sa[3][2];
  auto issue_stage = [&](int t) {
    const size_t row0 = ((size_t)blockIdx.x * TPB + t) * BM;
#pragma unroll
    for (int p = 0; p < 3; ++p) {
      const float* base = (p == 0) ? Qg : ((p == 1) ? Kg : Vg);
      const float* src  = base + row0 * DIM + soff;
      sa[p][0] = *(const float4*)src;
      sa[p][1] = *(const float4*)(src + 4);
    }
  };
  auto write_stage = [&](_Float16* sFn) {
#pragma unroll
    for (int p = 0; p < 3; ++p) {
      f16x8 h;
      h[0] = (_Float16)sa[p][0].x; h[1] = (_Float16)sa[p][0].y;
      h[2] = (_Float16)sa[p][0].z; h[3] = (_Float16)sa[p][0].w;
      h[4] = (_Float16)sa[p][1].x; h[5] = (_Float16)sa[p][1].y;
      h[6] = (_Float16)sa[p][1].z; h[7] = (_Float16)sa[p][1].w;
      *(f16x8*)(sFn + p * 4096 + sfrag) = h;
    }
  };

  // finale prefetch: lane's output cols are w*32 + c16*2 + {0,1}, rows kg*4+q
  float2 fv[4], fq[4];
  auto issue_finale = [&](int t) {
    const size_t row0 = ((size_t)blockIdx.x * TPB + t) * BM;
#pragma unroll
    for (int q = 0; q < 4; ++q) {
      const size_t gb = (row0 + kg * 4 + q) * DIM + w * 32 + c16 * 2;
      fv[q] = *(const float2*)(Vg + gb);
      fq[q] = *(const float2*)(Qg + gb);
    }
  };

  // prologue: stage tile 0
  issue_stage(0);
  write_stage(sF0);
  __syncthreads();

  for (int t = 0; t < TPB; ++t) {
    _Float16* sFc = (t & 1) ? sF1 : sF0;
    _Float16* sFn = (t & 1) ? sF0 : sF1;
    const bool doStage = (t + 1 < TPB);
    if (doStage) issue_stage(t + 1);     // next-tile loads in flight
    issue_finale(t);                     // this tile's finale Q,V in flight

    // ---- projections, swapped operands: accP holds P^T (row=c16, hd=kg*4+q) ----
    f32x4 accP[3] = {};
#pragma unroll
    for (int p = 0; p < 3; ++p)
#pragma unroll
      for (int ks = 0; ks < 8; ++ks) {
        const f16x8 af = *(const f16x8*)(sFc + (size_t)(((p * 8 + ks) * 64) + lane) * 8);
        accP[p] = __builtin_amdgcn_mfma_f32_16x16x32_f16(bwp[p * 8 + ks], af, accP[p], 0, 0, 0);
      }

    // ---- gated softmax: head-dim is register axis; reduce = 3 adds + 2 shfl ----
    float va[4];
    {
      float left[4], right[4];
      float pd0 = 0.f, pd1 = 0.f;
#pragma unroll
      for (int q = 0; q < 4; ++q) {
        const float qh = accP[0][q], kh = accP[1][q], vh = accP[2][q];
        left[q]  = kh * qh;
        right[q] = vh * qh;
        pd0 += left[q] * wl0q[q];
        pd1 += left[q] * wl1q[q];
      }
      pd0 += __shfl_xor(pd0, 16); pd0 += __shfl_xor(pd0, 32);
      pd1 += __shfl_xor(pd1, 16); pd1 += __shfl_xor(pd1, 32);
      const float m0 = 1.f / (1.f + __expf(-(pd0 + bl0)));
      const float m1 = 1.f / (1.f + __expf(-(pd1 + bl1)));
      const float mm = m0 * m1;
      float pnum = 0.f, pden = 0.f;
      float ev[4];
#pragma unroll
      for (int q = 0; q < 4; ++q) {
        ev[q] = __expf(left[q] * mm);    // |arg| <~ 40: f32-safe without max-sub
        pnum += ev[q] * wsq[q];
        pden += ev[q];
      }
      pnum += __shfl_xor(pnum, 16); pnum += __shfl_xor(pnum, 32);
      pden += __shfl_xor(pden, 16); pden += __shfl_xor(pden, 32);
      const float score = pnum / pden + bs0;
#pragma unroll
      for (int q = 0; q < 4; ++q) va[q] = score * right[q];
    }

    // ---- store V_att^T values into W_o A-fragment layout ----
    // V_att element (row=c16, k=w*16+kg*4+q); frag addr:
    // ((k>>5)*64 + ((k>>3)&3)*16 + row)*8 + (k&7)
#pragma unroll
    for (int q = 0; q < 4; ++q) {
      const int k = w * 16 + kg * 4 + q;
      sVAf[(size_t)((k >> 5) * 64 + ((k >> 3) & 3) * 16 + c16) * 8 + (k & 7)]
          = (_Float16)va[q];
    }
    __syncthreads();

    // ---- W_o: A = sVAf (LDS), B held; tiles nto = 2w, 2w+1 ----
    f32x4 accO[2] = {};
#pragma unroll
    for (int ks = 0; ks < 4; ++ks) {
      const f16x8 af = *(const f16x8*)(sVAf + (size_t)(ks * 64 + lane) * 8);
      accO[0] = __builtin_amdgcn_mfma_f32_16x16x32_f16(af, bo[ks],     accO[0], 0, 0, 0);
      accO[1] = __builtin_amdgcn_mfma_f32_16x16x32_f16(af, bo[4 + ks], accO[1], 0, 0, 0);
    }

    // ---- final: out = silu((V*Q) * V_att_out); pure VALU + store ----
    const size_t row0 = ((size_t)blockIdx.x * TPB + t) * BM;
#pragma unroll
    for (int q = 0; q < 4; ++q) {
      const size_t gb = (row0 + kg * 4 + q) * DIM + w * 32 + c16 * 2;
      const float att0 = fv[q].x * fq[q].x * accO[0][q];
      const float att1 = fv[q].y * fq[q].y * accO[1][q];
      float2 o;
      o.x = att0 / (1.f + __expf(-att0));
      o.y = att1 / (1.f + __expf(-att1));
      *(float2*)(outg + gb) = o;
    }

    // ---- write next tile's fragments; loop-end barrier covers all hazards ----
    if (doStage) {
      write_stage(sFn);
      __syncthreads();
    }
  }
}

// ---------------------------------------------------------------------------
extern "C" void kernel_launch(void* const* d_in, const int* in_sizes, int n_in,
                              void* d_out, int out_size, void* d_ws, size_t ws_size,
                              hipStream_t stream) {
  const float* Q  = (const float*)d_in[0];
  const float* K  = (const float*)d_in[1];
  const float* V  = (const float*)d_in[2];
  const float* Wq = (const float*)d_in[3];
  const float* Wk = (const float*)d_in[4];
  const float* Wv = (const float*)d_in[5];
  const float* Wo = (const float*)d_in[6];
  const float* Wl = (const float*)d_in[7];
  const float* bl = (const float*)d_in[8];
  const float* Ws = (const float*)d_in[9];
  const float* bs = (const float*)d_in[10];
  _Float16* wt = (_Float16*)d_ws;   // 131072 halves = 256 KB of scratch
  float* out = (float*)d_out;

  pack_w<<<512, 256, 0, stream>>>(Wq, Wk, Wv, Wo, wt);
  uan_main<<<NBLK, 512, 0, stream>>>(Q, K, V, wt, Wl, bl, Ws, bs, out);
}

// Round 8
// 151.931 us; speedup vs baseline: 1.0034x; 1.0034x over previous
//
#include <hip/hip_runtime.h>
#include <hip/hip_fp16.h>
#include <stdint.h>

// Problem constants (hardcoded per reference)
#define NROWS 131072   // B*L
#define DIM   256      // D
#define HDK   128      // H*DK
#define BM    16       // rows per tile
#define TPB   8        // tiles per block
#define NBLK  (NROWS / BM / TPB)   // 1024 blocks

typedef _Float16 f16x8 __attribute__((ext_vector_type(8)));
typedef float    f32x4 __attribute__((ext_vector_type(4)));

// ---------------------------------------------------------------------------
// Pack W_q, W_k, W_v (256x128) and W_o (128x256) into fragment-linear fp16.
// Proj p at p*32768: frag idx = ((nt*8 + ks)*64 + lane)*8 + j,
//   value = W[ks*32 + (lane>>4)*8 + j][nt*16 + (lane&15)]   (nt = head)
// W_o at 98304: frag idx = ((nto*4 + ks)*64 + lane)*8 + j, COLUMN PERMUTE:
//   actual col n = (nto>>1)*32 + (lane&15)*2 + (nto&1)
// so wave w (tiles nto=2w,2w+1) gives each lane 2 consecutive output columns.
// ---------------------------------------------------------------------------
__global__ void pack_w(const float* __restrict__ Wq, const float* __restrict__ Wk,
                       const float* __restrict__ Wv, const float* __restrict__ Wo,
                       _Float16* __restrict__ wt) {
  int t = blockIdx.x * 256 + threadIdx.x;   // 0 .. 131071
  int seg = t >> 15;                        // 0..3
  int i = t & 32767;
  int j = i & 7;
  int l = (i >> 3) & 63;
  int rest = i >> 9;                        // nt*KS + ks
  const float* W;
  int N, k, n;
  if (seg < 3) {
    W = (seg == 0) ? Wq : ((seg == 1) ? Wk : Wv);
    N = HDK;
    int ks = rest & 7, nt = rest >> 3;
    k = ks * 32 + ((l >> 4) << 3) + j;      // 0..255
    n = nt * 16 + (l & 15);                 // 0..127
  } else {
    W = Wo;
    N = DIM;
    int ks = rest & 3, nt = rest >> 2;      // nt = nto in 0..15
    k = ks * 32 + ((l >> 4) << 3) + j;      // 0..127
    n = ((nt >> 1) << 5) + ((l & 15) << 1) + (nt & 1);  // permuted column
  }
  wt[t] = (_Float16)W[k * N + n];
}

// ---------------------------------------------------------------------------
// v8 = v6 structure (persistent-weight waves, swapped-operand proj ->
// register-axis softmax, double-buffered pipelined staging, finale prefetch)
// with persistence made REAL:
//  - amdgpu_waves_per_eu(2,2): occupancy pinned at 2 waves/SIMD -> 256-VGPR
//    regalloc budget -> compiler can hoist all 40 weight fragments.
//  - asm keep-alive on every held fragment inside the tile loop: values are
//    loop-live in VGPRs, cannot be rematerialized from wt (the R5-R7 silent
//    failure: VGPR_Count 104-108 proved per-tile L2 reloads).
// ---------------------------------------------------------------------------
__global__ __launch_bounds__(512)
__attribute__((amdgpu_waves_per_eu(2, 2)))
void uan_main(const float* __restrict__ Qg, const float* __restrict__ Kg,
              const float* __restrict__ Vg, const _Float16* __restrict__ wt,
              const float* __restrict__ Wl, const float* __restrict__ blv,
              const float* __restrict__ Wsv, const float* __restrict__ bsv,
              float* __restrict__ outg) {
  __shared__ __align__(16) _Float16 sF0[1536 * 8];   // 24576 B
  __shared__ __align__(16) _Float16 sF1[1536 * 8];   // 24576 B
  __shared__ __align__(16) _Float16 sVAf[256 * 8];   //  4096 B

  const int tid  = threadIdx.x;
  const int lane = tid & 63;
  const int w    = tid >> 6;        // wave 0..7 == head
  const int c16  = lane & 15;
  const int kg   = lane >> 4;

  // ---- held B-fragments (loaded once per block life) ----
  f16x8 bwp[24];   // proj: [p*8 + ks], head w
#pragma unroll
  for (int p = 0; p < 3; ++p)
#pragma unroll
    for (int ks = 0; ks < 8; ++ks)
      bwp[p * 8 + ks] = *(const f16x8*)(wt + p * 32768 +
                         (size_t)(((w * 8 + ks) * 64) + lane) * 8);
  f16x8 bo[8];     // W_o: [nt*4 + ks], tiles nto = 2w, 2w+1
#pragma unroll
  for (int nt = 0; nt < 2; ++nt)
#pragma unroll
    for (int ks = 0; ks < 4; ++ks)
      bo[nt * 4 + ks] = *(const f16x8*)(wt + 98304 +
                         (size_t)((((2 * w + nt) * 4 + ks) * 64) + lane) * 8);

  const float bl0 = blv[0], bl1 = blv[1], bs0 = bsv[0];
  // per-register softmax constants: hd = kg*4 + q
  float wl0q[4], wl1q[4], wsq[4];
#pragma unroll
  for (int q = 0; q < 4; ++q) {
    wl0q[q] = Wl[kg * 4 + q];
    wl1q[q] = Wl[16 + kg * 4 + q];
    wsq[q]  = Wsv[kg * 4 + q];
  }

  // staging: thread stages row (row0+c16)'s cols [w*32+kg*8, +8) of each plane
  const size_t soff  = (size_t)c16 * DIM + w * 32 + kg * 8;
  const size_t sfrag = (size_t)(w * 64 + lane) * 8;   // + p*4096 per plane

  float4 sa[3][2];
  auto issue_stage = [&](int t) {
    const size_t row0 = ((size_t)blockIdx.x * TPB + t) * BM;
#pragma unroll
    for (int p = 0; p < 3; ++p) {
      const float* base = (p == 0) ? Qg : ((p == 1) ? Kg : Vg);
      const float* src  = base + row0 * DIM + soff;
      sa[p][0] = *(const float4*)src;
      sa[p][1] = *(const float4*)(src + 4);
    }
  };
  auto write_stage = [&](_Float16* sFn) {
#pragma unroll
    for (int p = 0; p < 3; ++p) {
      f16x8 h;
      h[0] = (_Float16)sa[p][0].x; h[1] = (_Float16)sa[p][0].y;
      h[2] = (_Float16)sa[p][0].z; h[3] = (_Float16)sa[p][0].w;
      h[4] = (_Float16)sa[p][1].x; h[5] = (_Float16)sa[p][1].y;
      h[6] = (_Float16)sa[p][1].z; h[7] = (_Float16)sa[p][1].w;
      *(f16x8*)(sFn + p * 4096 + sfrag) = h;
    }
  };

  // finale prefetch: lane's output cols are w*32 + c16*2 + {0,1}, rows kg*4+q
  float2 fv[4], fq[4];
  auto issue_finale = [&](int t) {
    const size_t row0 = ((size_t)blockIdx.x * TPB + t) * BM;
#pragma unroll
    for (int q = 0; q < 4; ++q) {
      const size_t gb = (row0 + kg * 4 + q) * DIM + w * 32 + c16 * 2;
      fv[q] = *(const float2*)(Vg + gb);
      fq[q] = *(const float2*)(Qg + gb);
    }
  };

  // prologue: stage tile 0
  issue_stage(0);
  write_stage(sF0);
  __syncthreads();

  for (int t = 0; t < TPB; ++t) {
    // keep-alive: held weight fragments must be live VGPRs each iteration
#pragma unroll
    for (int i = 0; i < 24; ++i) asm volatile("" : "+v"(bwp[i]));
#pragma unroll
    for (int i = 0; i < 8; ++i)  asm volatile("" : "+v"(bo[i]));

    _Float16* sFc = (t & 1) ? sF1 : sF0;
    _Float16* sFn = (t & 1) ? sF0 : sF1;
    const bool doStage = (t + 1 < TPB);
    if (doStage) issue_stage(t + 1);     // next-tile loads in flight
    issue_finale(t);                     // this tile's finale Q,V in flight

    // ---- projections, swapped operands: accP holds P^T (row=c16, hd=kg*4+q) ----
    f32x4 accP[3] = {};
#pragma unroll
    for (int p = 0; p < 3; ++p)
#pragma unroll
      for (int ks = 0; ks < 8; ++ks) {
        const f16x8 af = *(const f16x8*)(sFc + (size_t)(((p * 8 + ks) * 64) + lane) * 8);
        accP[p] = __builtin_amdgcn_mfma_f32_16x16x32_f16(bwp[p * 8 + ks], af, accP[p], 0, 0, 0);
      }

    // ---- gated softmax: head-dim is register axis; reduce = 3 adds + 2 shfl ----
    float va[4];
    {
      float left[4], right[4];
      float pd0 = 0.f, pd1 = 0.f;
#pragma unroll
      for (int q = 0; q < 4; ++q) {
        const float qh = accP[0][q], kh = accP[1][q], vh = accP[2][q];
        left[q]  = kh * qh;
        right[q] = vh * qh;
        pd0 += left[q] * wl0q[q];
        pd1 += left[q] * wl1q[q];
      }
      pd0 += __shfl_xor(pd0, 16); pd0 += __shfl_xor(pd0, 32);
      pd1 += __shfl_xor(pd1, 16); pd1 += __shfl_xor(pd1, 32);
      const float m0 = 1.f / (1.f + __expf(-(pd0 + bl0)));
      const float m1 = 1.f / (1.f + __expf(-(pd1 + bl1)));
      const float mm = m0 * m1;
      float pnum = 0.f, pden = 0.f;
      float ev[4];
#pragma unroll
      for (int q = 0; q < 4; ++q) {
        ev[q] = __expf(left[q] * mm);    // |arg| <~ 40: f32-safe without max-sub
        pnum += ev[q] * wsq[q];
        pden += ev[q];
      }
      pnum += __shfl_xor(pnum, 16); pnum += __shfl_xor(pnum, 32);
      pden += __shfl_xor(pden, 16); pden += __shfl_xor(pden, 32);
      const float score = pnum / pden + bs0;
#pragma unroll
      for (int q = 0; q < 4; ++q) va[q] = score * right[q];
    }

    // ---- store V_att^T values into W_o A-fragment layout ----
    // V_att element (row=c16, k=w*16+kg*4+q); frag addr:
    // ((k>>5)*64 + ((k>>3)&3)*16 + row)*8 + (k&7)
#pragma unroll
    for (int q = 0; q < 4; ++q) {
      const int k = w * 16 + kg * 4 + q;
      sVAf[(size_t)((k >> 5) * 64 + ((k >> 3) & 3) * 16 + c16) * 8 + (k & 7)]
          = (_Float16)va[q];
    }
    __syncthreads();

    // ---- W_o: A = sVAf (LDS), B held; tiles nto = 2w, 2w+1 ----
    f32x4 accO[2] = {};
#pragma unroll
    for (int ks = 0; ks < 4; ++ks) {
      const f16x8 af = *(const f16x8*)(sVAf + (size_t)(ks * 64 + lane) * 8);
      accO[0] = __builtin_amdgcn_mfma_f32_16x16x32_f16(af, bo[ks],     accO[0], 0, 0, 0);
      accO[1] = __builtin_amdgcn_mfma_f32_16x16x32_f16(af, bo[4 + ks], accO[1], 0, 0, 0);
    }

    // ---- final: out = silu((V*Q) * V_att_out); pure VALU + store ----
    const size_t row0 = ((size_t)blockIdx.x * TPB + t) * BM;
#pragma unroll
    for (int q = 0; q < 4; ++q) {
      const size_t gb = (row0 + kg * 4 + q) * DIM + w * 32 + c16 * 2;
      const float att0 = fv[q].x * fq[q].x * accO[0][q];
      const float att1 = fv[q].y * fq[q].y * accO[1][q];
      float2 o;
      o.x = att0 / (1.f + __expf(-att0));
      o.y = att1 / (1.f + __expf(-att1));
      *(float2*)(outg + gb) = o;
    }

    // ---- write next tile's fragments; loop-end barrier covers all hazards ----
    if (doStage) {
      write_stage(sFn);
      __syncthreads();
    }
  }
}

// ---------------------------------------------------------------------------
extern "C" void kernel_launch(void* const* d_in, const int* in_sizes, int n_in,
                              void* d_out, int out_size, void* d_ws, size_t ws_size,
                              hipStream_t stream) {
  const float* Q  = (const float*)d_in[0];
  const float* K  = (const float*)d_in[1];
  const float* V  = (const float*)d_in[2];
  const float* Wq = (const float*)d_in[3];
  const float* Wk = (const float*)d_in[4];
  const float* Wv = (const float*)d_in[5];
  const float* Wo = (const float*)d_in[6];
  const float* Wl = (const float*)d_in[7];
  const float* bl = (const float*)d_in[8];
  const float* Ws = (const float*)d_in[9];
  const float* bs = (const float*)d_in[10];
  _Float16* wt = (_Float16*)d_ws;   // 131072 halves = 256 KB of scratch
  float* out = (float*)d_out;

  pack_w<<<512, 256, 0, stream>>>(Wq, Wk, Wv, Wo, wt);
  uan_main<<<NBLK, 512, 0, stream>>>(Q, K, V, wt, Wl, bl, Ws, bs, out);
}

// Round 9
// 150.742 us; speedup vs baseline: 1.0113x; 1.0079x over previous
//
#include <hip/hip_runtime.h>
#include <hip/hip_fp16.h>
#include <stdint.h>

// Problem constants (hardcoded per reference)
#define NROWS 131072   // B*L
#define DIM   256      // D
#define HDK   128      // H*DK
#define BM    16       // rows per tile
#define TPB   8        // tiles per block
#define NBLK  (NROWS / BM / TPB)   // 1024 blocks

typedef _Float16 f16x8 __attribute__((ext_vector_type(8)));
typedef float    f32x4 __attribute__((ext_vector_type(4)));

// LDS-ordering barrier WITHOUT the __syncthreads vmcnt(0) drain:
// waves finish their own LDS ops, then sync; global loads stay in flight.
#define LDS_BARRIER() asm volatile("s_waitcnt lgkmcnt(0)\ns_barrier" ::: "memory")

// ---------------------------------------------------------------------------
// Pack W_q, W_k, W_v (256x128) and W_o (128x256) into fragment-linear fp16.
// Proj p at p*32768: frag idx = ((nt*8 + ks)*64 + lane)*8 + j,
//   value = W[ks*32 + (lane>>4)*8 + j][nt*16 + (lane&15)]   (nt = head)
// W_o at 98304: frag idx = ((nto*4 + ks)*64 + lane)*8 + j, COLUMN PERMUTE:
//   actual col n = (nto>>1)*32 + (lane&15)*2 + (nto&1)
// so wave w (tiles nto=2w,2w+1) gives each lane 2 consecutive output columns.
// ---------------------------------------------------------------------------
__global__ void pack_w(const float* __restrict__ Wq, const float* __restrict__ Wk,
                       const float* __restrict__ Wv, const float* __restrict__ Wo,
                       _Float16* __restrict__ wt) {
  int t = blockIdx.x * 256 + threadIdx.x;   // 0 .. 131071
  int seg = t >> 15;                        // 0..3
  int i = t & 32767;
  int j = i & 7;
  int l = (i >> 3) & 63;
  int rest = i >> 9;                        // nt*KS + ks
  const float* W;
  int N, k, n;
  if (seg < 3) {
    W = (seg == 0) ? Wq : ((seg == 1) ? Wk : Wv);
    N = HDK;
    int ks = rest & 7, nt = rest >> 3;
    k = ks * 32 + ((l >> 4) << 3) + j;      // 0..255
    n = nt * 16 + (l & 15);                 // 0..127
  } else {
    W = Wo;
    N = DIM;
    int ks = rest & 3, nt = rest >> 2;      // nt = nto in 0..15
    k = ks * 32 + ((l >> 4) << 3) + j;      // 0..127
    n = ((nt >> 1) << 5) + ((l & 15) << 1) + (nt & 1);  // permuted column
  }
  wt[t] = (_Float16)W[k * N + n];
}

// ---------------------------------------------------------------------------
// v9 = v6 + barrier surgery:
//  - ONE raw-s_barrier per tile (lgkmcnt-only wait, no vmcnt drain -> global
//    prefetches genuinely cross barriers; the R6-R8 pipeline was being
//    force-drained by __syncthreads' vmcnt(0)).
//  - sVAf double-buffered so sVAf-write(t) and W_o-read(t) straddle the
//    single barrier with no extra sync.
//  - loop-rotated staging: tile t+2's loads issued before tile t's barrier
//    -> each staging load gets a full tile of latency cover.
// Per-tile order: finale-issue(t) | proj(t) | softmax(t) | sVAf[t&1] write |
//   write_stage(t+1) | issue_stage(t+2) | [lgkm+barrier] | W_o(t) | finale(t)
// ---------------------------------------------------------------------------
__launch_bounds__(512, 2)
__global__ void uan_main(const float* __restrict__ Qg, const float* __restrict__ Kg,
                         const float* __restrict__ Vg, const _Float16* __restrict__ wt,
                         const float* __restrict__ Wl, const float* __restrict__ blv,
                         const float* __restrict__ Wsv, const float* __restrict__ bsv,
                         float* __restrict__ outg) {
  __shared__ __align__(16) _Float16 sF0[1536 * 8];   // 24576 B
  __shared__ __align__(16) _Float16 sF1[1536 * 8];   // 24576 B
  __shared__ __align__(16) _Float16 sVA0[256 * 8];   //  4096 B
  __shared__ __align__(16) _Float16 sVA1[256 * 8];   //  4096 B

  const int tid  = threadIdx.x;
  const int lane = tid & 63;
  const int w    = tid >> 6;        // wave 0..7 == head
  const int c16  = lane & 15;
  const int kg   = lane >> 4;

  // ---- held B-fragments (loaded once; compiler may re-load, acceptable) ----
  f16x8 bwp[24];   // proj: [p*8 + ks], head w
#pragma unroll
  for (int p = 0; p < 3; ++p)
#pragma unroll
    for (int ks = 0; ks < 8; ++ks)
      bwp[p * 8 + ks] = *(const f16x8*)(wt + p * 32768 +
                         (size_t)(((w * 8 + ks) * 64) + lane) * 8);
  f16x8 bo[8];     // W_o: [nt*4 + ks], tiles nto = 2w, 2w+1
#pragma unroll
  for (int nt = 0; nt < 2; ++nt)
#pragma unroll
    for (int ks = 0; ks < 4; ++ks)
      bo[nt * 4 + ks] = *(const f16x8*)(wt + 98304 +
                         (size_t)((((2 * w + nt) * 4 + ks) * 64) + lane) * 8);

  const float bl0 = blv[0], bl1 = blv[1], bs0 = bsv[0];
  // per-register softmax constants: hd = kg*4 + q
  float wl0q[4], wl1q[4], wsq[4];
#pragma unroll
  for (int q = 0; q < 4; ++q) {
    wl0q[q] = Wl[kg * 4 + q];
    wl1q[q] = Wl[16 + kg * 4 + q];
    wsq[q]  = Wsv[kg * 4 + q];
  }

  // staging: thread stages row (row0+c16)'s cols [w*32+kg*8, +8) of each plane
  const size_t soff  = (size_t)c16 * DIM + w * 32 + kg * 8;
  const size_t sfrag = (size_t)(w * 64 + lane) * 8;   // + p*4096 per plane

  float4 sa[3][2];
  auto issue_stage = [&](int t) {
    const size_t row0 = ((size_t)blockIdx.x * TPB + t) * BM;
#pragma unroll
    for (int p = 0; p < 3; ++p) {
      const float* base = (p == 0) ? Qg : ((p == 1) ? Kg : Vg);
      const float* src  = base + row0 * DIM + soff;
      sa[p][0] = *(const float4*)src;
      sa[p][1] = *(const float4*)(src + 4);
    }
  };
  auto write_stage = [&](_Float16* sFn) {
#pragma unroll
    for (int p = 0; p < 3; ++p) {
      f16x8 h;
      h[0] = (_Float16)sa[p][0].x; h[1] = (_Float16)sa[p][0].y;
      h[2] = (_Float16)sa[p][0].z; h[3] = (_Float16)sa[p][0].w;
      h[4] = (_Float16)sa[p][1].x; h[5] = (_Float16)sa[p][1].y;
      h[6] = (_Float16)sa[p][1].z; h[7] = (_Float16)sa[p][1].w;
      *(f16x8*)(sFn + p * 4096 + sfrag) = h;
    }
  };

  // finale prefetch: lane's output cols are w*32 + c16*2 + {0,1}, rows kg*4+q
  float2 fv[4], fq[4];
  auto issue_finale = [&](int t) {
    const size_t row0 = ((size_t)blockIdx.x * TPB + t) * BM;
#pragma unroll
    for (int q = 0; q < 4; ++q) {
      const size_t gb = (row0 + kg * 4 + q) * DIM + w * 32 + c16 * 2;
      fv[q] = *(const float2*)(Vg + gb);
      fq[q] = *(const float2*)(Qg + gb);
    }
  };

  // prologue: stage tile 0, pre-issue tile 1
  issue_stage(0);
  write_stage(sF0);
  issue_stage(1);
  LDS_BARRIER();

  for (int t = 0; t < TPB; ++t) {
    _Float16* sFc = (t & 1) ? sF1 : sF0;
    _Float16* sFn = (t & 1) ? sF0 : sF1;
    _Float16* sVc = (t & 1) ? sVA1 : sVA0;
    issue_finale(t);                     // this tile's finale Q,V in flight

    // ---- projections, swapped operands: accP holds P^T (row=c16, hd=kg*4+q) ----
    f32x4 accP[3] = {};
#pragma unroll
    for (int p = 0; p < 3; ++p)
#pragma unroll
      for (int ks = 0; ks < 8; ++ks) {
        const f16x8 af = *(const f16x8*)(sFc + (size_t)(((p * 8 + ks) * 64) + lane) * 8);
        accP[p] = __builtin_amdgcn_mfma_f32_16x16x32_f16(bwp[p * 8 + ks], af, accP[p], 0, 0, 0);
      }

    // ---- gated softmax: head-dim is register axis; reduce = 3 adds + 2 shfl ----
    float va[4];
    {
      float left[4], right[4];
      float pd0 = 0.f, pd1 = 0.f;
#pragma unroll
      for (int q = 0; q < 4; ++q) {
        const float qh = accP[0][q], kh = accP[1][q], vh = accP[2][q];
        left[q]  = kh * qh;
        right[q] = vh * qh;
        pd0 += left[q] * wl0q[q];
        pd1 += left[q] * wl1q[q];
      }
      pd0 += __shfl_xor(pd0, 16); pd0 += __shfl_xor(pd0, 32);
      pd1 += __shfl_xor(pd1, 16); pd1 += __shfl_xor(pd1, 32);
      const float m0 = 1.f / (1.f + __expf(-(pd0 + bl0)));
      const float m1 = 1.f / (1.f + __expf(-(pd1 + bl1)));
      const float mm = m0 * m1;
      float pnum = 0.f, pden = 0.f;
      float ev[4];
#pragma unroll
      for (int q = 0; q < 4; ++q) {
        ev[q] = __expf(left[q] * mm);    // |arg| <~ 40: f32-safe without max-sub
        pnum += ev[q] * wsq[q];
        pden += ev[q];
      }
      pnum += __shfl_xor(pnum, 16); pnum += __shfl_xor(pnum, 32);
      pden += __shfl_xor(pden, 16); pden += __shfl_xor(pden, 32);
      const float score = pnum / pden + bs0;
#pragma unroll
      for (int q = 0; q < 4; ++q) va[q] = score * right[q];
    }

    // ---- store V_att^T values into W_o A-fragment layout (double-buffered) ----
    // V_att element (row=c16, k=w*16+kg*4+q); frag addr:
    // ((k>>5)*64 + ((k>>3)&3)*16 + row)*8 + (k&7)
#pragma unroll
    for (int q = 0; q < 4; ++q) {
      const int k = w * 16 + kg * 4 + q;
      sVc[(size_t)((k >> 5) * 64 + ((k >> 3) & 3) * 16 + c16) * 8 + (k & 7)]
          = (_Float16)va[q];
    }

    // ---- next-tile staging write; tile-after-next issue (full-tile cover) ----
    if (t + 1 < TPB) write_stage(sFn);
    if (t + 2 < TPB) issue_stage(t + 2);

    LDS_BARRIER();   // the ONLY barrier per tile

    // ---- W_o: A = sVc (LDS), B held; tiles nto = 2w, 2w+1 ----
    f32x4 accO[2] = {};
#pragma unroll
    for (int ks = 0; ks < 4; ++ks) {
      const f16x8 af = *(const f16x8*)(sVc + (size_t)(ks * 64 + lane) * 8);
      accO[0] = __builtin_amdgcn_mfma_f32_16x16x32_f16(af, bo[ks],     accO[0], 0, 0, 0);
      accO[1] = __builtin_amdgcn_mfma_f32_16x16x32_f16(af, bo[4 + ks], accO[1], 0, 0, 0);
    }

    // ---- final: out = silu((V*Q) * V_att_out); pure VALU + store ----
    const size_t row0 = ((size_t)blockIdx.x * TPB + t) * BM;
#pragma unroll
    for (int q = 0; q < 4; ++q) {
      const size_t gb = (row0 + kg * 4 + q) * DIM + w * 32 + c16 * 2;
      const float att0 = fv[q].x * fq[q].x * accO[0][q];
      const float att1 = fv[q].y * fq[q].y * accO[1][q];
      float2 o;
      o.x = att0 / (1.f + __expf(-att0));
      o.y = att1 / (1.f + __expf(-att1));
      *(float2*)(outg + gb) = o;
    }
  }
}

// ---------------------------------------------------------------------------
extern "C" void kernel_launch(void* const* d_in, const int* in_sizes, int n_in,
                              void* d_out, int out_size, void* d_ws, size_t ws_size,
                              hipStream_t stream) {
  const float* Q  = (const float*)d_in[0];
  const float* K  = (const float*)d_in[1];
  const float* V  = (const float*)d_in[2];
  const float* Wq = (const float*)d_in[3];
  const float* Wk = (const float*)d_in[4];
  const float* Wv = (const float*)d_in[5];
  const float* Wo = (const float*)d_in[6];
  const float* Wl = (const float*)d_in[7];
  const float* bl = (const float*)d_in[8];
  const float* Ws = (const float*)d_in[9];
  const float* bs = (const float*)d_in[10];
  _Float16* wt = (_Float16*)d_ws;   // 131072 halves = 256 KB of scratch
  float* out = (float*)d_out;

  pack_w<<<512, 256, 0, stream>>>(Wq, Wk, Wv, Wo, wt);
  uan_main<<<NBLK, 512, 0, stream>>>(Q, K, V, wt, Wl, bl, Ws, bs, out);
}

// Round 10
// 135.016 us; speedup vs baseline: 1.1291x; 1.1165x over previous
//
#include <hip/hip_runtime.h>
#include <hip/hip_fp16.h>
#include <stdint.h>

// Problem constants (hardcoded per reference)
#define NROWS 131072   // B*L
#define DIM   256      // D
#define HDK   128      // H*DK
#define BM    16       // rows per tile
#define TPB   16       // tiles per block
#define NBLK  (NROWS / BM / TPB)   // 512 blocks = 256 CUs x 2 resident

typedef _Float16 f16x8 __attribute__((ext_vector_type(8)));
typedef _Float16 f16x2 __attribute__((ext_vector_type(2)));
typedef float    f32x4 __attribute__((ext_vector_type(4)));

// LDS-ordering barrier WITHOUT the __syncthreads vmcnt(0) drain.
#define LDS_BARRIER() asm volatile("s_waitcnt lgkmcnt(0)\ns_barrier" ::: "memory")

// ---------------------------------------------------------------------------
// Pack W_q, W_k, W_v (256x128) and W_o (128x256) into fragment-linear fp16.
// Proj p at p*32768: frag idx = ((nt*8 + ks)*64 + lane)*8 + j,
//   value = W[ks*32 + (lane>>4)*8 + j][nt*16 + (lane&15)]   (nt = head)
// W_o at 98304: frag idx = ((nto*4 + ks)*64 + lane)*8 + j, COLUMN PERMUTE:
//   actual col n = (nto>>1)*32 + (lane&15)*2 + (nto&1)
// ---------------------------------------------------------------------------
__global__ void pack_w(const float* __restrict__ Wq, const float* __restrict__ Wk,
                       const float* __restrict__ Wv, const float* __restrict__ Wo,
                       _Float16* __restrict__ wt) {
  int t = blockIdx.x * 256 + threadIdx.x;   // 0 .. 131071
  int seg = t >> 15;                        // 0..3
  int i = t & 32767;
  int j = i & 7;
  int l = (i >> 3) & 63;
  int rest = i >> 9;                        // nt*KS + ks
  const float* W;
  int N, k, n;
  if (seg < 3) {
    W = (seg == 0) ? Wq : ((seg == 1) ? Wk : Wv);
    N = HDK;
    int ks = rest & 7, nt = rest >> 3;
    k = ks * 32 + ((l >> 4) << 3) + j;      // 0..255
    n = nt * 16 + (l & 15);                 // 0..127
  } else {
    W = Wo;
    N = DIM;
    int ks = rest & 3, nt = rest >> 2;      // nt = nto in 0..15
    k = ks * 32 + ((l >> 4) << 3) + j;      // 0..127
    n = ((nt >> 1) << 5) + ((l & 15) << 1) + (nt & 1);  // permuted column
  }
  wt[t] = (_Float16)W[k * N + n];
}

// ---------------------------------------------------------------------------
// v10 = v6/v9 champion structure with the finale's global Q,V re-read DELETED:
//  - vq = V*Q read as fp16 pairs from the ALREADY-STAGED sF LDS buffer
//    (8 ds_read_u32/thread/tile replace 8 global loads -> per-tile VMEM 18->10)
//  - vq reads hoisted pre-barrier: all sF[t&1] reads complete before
//    barrier(t); next write to that buffer is after barrier(t). One barrier
//    per tile covers every LDS hazard (checked buffer-by-buffer).
//  - staging distance back to t+1 (R9's t+2 raised FETCH 205->290 MB)
//  - TPB=16 -> 512 blocks = full residency (2 blocks/CU), weight fill 1x.
// ---------------------------------------------------------------------------
__launch_bounds__(512, 2)
__global__ void uan_main(const float* __restrict__ Qg, const float* __restrict__ Kg,
                         const float* __restrict__ Vg, const _Float16* __restrict__ wt,
                         const float* __restrict__ Wl, const float* __restrict__ blv,
                         const float* __restrict__ Wsv, const float* __restrict__ bsv,
                         float* __restrict__ outg) {
  __shared__ __align__(16) _Float16 sF0[1536 * 8];   // 24576 B
  __shared__ __align__(16) _Float16 sF1[1536 * 8];   // 24576 B
  __shared__ __align__(16) _Float16 sVA0[256 * 8];   //  4096 B
  __shared__ __align__(16) _Float16 sVA1[256 * 8];   //  4096 B

  const int tid  = threadIdx.x;
  const int lane = tid & 63;
  const int w    = tid >> 6;        // wave 0..7 == head
  const int c16  = lane & 15;
  const int kg   = lane >> 4;

  // ---- held B-fragments (loaded once; compiler may re-load, acceptable) ----
  f16x8 bwp[24];   // proj: [p*8 + ks], head w
#pragma unroll
  for (int p = 0; p < 3; ++p)
#pragma unroll
    for (int ks = 0; ks < 8; ++ks)
      bwp[p * 8 + ks] = *(const f16x8*)(wt + p * 32768 +
                         (size_t)(((w * 8 + ks) * 64) + lane) * 8);
  f16x8 bo[8];     // W_o: [nt*4 + ks], tiles nto = 2w, 2w+1
#pragma unroll
  for (int nt = 0; nt < 2; ++nt)
#pragma unroll
    for (int ks = 0; ks < 4; ++ks)
      bo[nt * 4 + ks] = *(const f16x8*)(wt + 98304 +
                         (size_t)((((2 * w + nt) * 4 + ks) * 64) + lane) * 8);

  const float bl0 = blv[0], bl1 = blv[1], bs0 = bsv[0];
  // per-register softmax constants: hd = kg*4 + q
  float wl0q[4], wl1q[4], wsq[4];
#pragma unroll
  for (int q = 0; q < 4; ++q) {
    wl0q[q] = Wl[kg * 4 + q];
    wl1q[q] = Wl[16 + kg * 4 + q];
    wsq[q]  = Wsv[kg * 4 + q];
  }

  // staging: thread stages row (row0+c16)'s cols [w*32+kg*8, +8) of each plane
  const size_t soff  = (size_t)c16 * DIM + w * 32 + kg * 8;
  const size_t sfrag = (size_t)(w * 64 + lane) * 8;   // + p*4096 per plane

  float4 sa[3][2];
  auto issue_stage = [&](int t) {
    const size_t row0 = ((size_t)blockIdx.x * TPB + t) * BM;
#pragma unroll
    for (int p = 0; p < 3; ++p) {
      const float* base = (p == 0) ? Qg : ((p == 1) ? Kg : Vg);
      const float* src  = base + row0 * DIM + soff;
      sa[p][0] = *(const float4*)src;
      sa[p][1] = *(const float4*)(src + 4);
    }
  };
  auto write_stage = [&](_Float16* sFn) {
#pragma unroll
    for (int p = 0; p < 3; ++p) {
      f16x8 h;
      h[0] = (_Float16)sa[p][0].x; h[1] = (_Float16)sa[p][0].y;
      h[2] = (_Float16)sa[p][0].z; h[3] = (_Float16)sa[p][0].w;
      h[4] = (_Float16)sa[p][1].x; h[5] = (_Float16)sa[p][1].y;
      h[6] = (_Float16)sa[p][1].z; h[7] = (_Float16)sa[p][1].w;
      *(f16x8*)(sFn + p * 4096 + sfrag) = h;
    }
  };

  // prologue: stage tile 0
  issue_stage(0);
  write_stage(sF0);
  LDS_BARRIER();

  for (int t = 0; t < TPB; ++t) {
    _Float16* sFc = (t & 1) ? sF1 : sF0;
    _Float16* sFn = (t & 1) ? sF0 : sF1;
    _Float16* sVc = (t & 1) ? sVA1 : sVA0;
    const bool more = (t + 1 < TPB);
    if (more) issue_stage(t + 1);        // next-tile global loads in flight

    // ---- projections, swapped operands: accP holds P^T (row=c16, hd=kg*4+q) ----
    f32x4 accP[3] = {};
#pragma unroll
    for (int p = 0; p < 3; ++p)
#pragma unroll
      for (int ks = 0; ks < 8; ++ks) {
        const f16x8 af = *(const f16x8*)(sFc + (size_t)(((p * 8 + ks) * 64) + lane) * 8);
        accP[p] = __builtin_amdgcn_mfma_f32_16x16x32_f16(bwp[p * 8 + ks], af, accP[p], 0, 0, 0);
      }

    // ---- gated softmax: head-dim is register axis; reduce = 3 adds + 2 shfl ----
    float va[4];
    {
      float left[4], right[4];
      float pd0 = 0.f, pd1 = 0.f;
#pragma unroll
      for (int q = 0; q < 4; ++q) {
        const float qh = accP[0][q], kh = accP[1][q], vh = accP[2][q];
        left[q]  = kh * qh;
        right[q] = vh * qh;
        pd0 += left[q] * wl0q[q];
        pd1 += left[q] * wl1q[q];
      }
      pd0 += __shfl_xor(pd0, 16); pd0 += __shfl_xor(pd0, 32);
      pd1 += __shfl_xor(pd1, 16); pd1 += __shfl_xor(pd1, 32);
      const float m0 = 1.f / (1.f + __expf(-(pd0 + bl0)));
      const float m1 = 1.f / (1.f + __expf(-(pd1 + bl1)));
      const float mm = m0 * m1;
      float pnum = 0.f, pden = 0.f;
      float ev[4];
#pragma unroll
      for (int q = 0; q < 4; ++q) {
        ev[q] = __expf(left[q] * mm);    // |arg| <~ 40: f32-safe without max-sub
        pnum += ev[q] * wsq[q];
        pden += ev[q];
      }
      pnum += __shfl_xor(pnum, 16); pnum += __shfl_xor(pnum, 32);
      pden += __shfl_xor(pden, 16); pden += __shfl_xor(pden, 32);
      const float score = pnum / pden + bs0;
#pragma unroll
      for (int q = 0; q < 4; ++q) va[q] = score * right[q];
    }

    // ---- store V_att^T values into W_o A-fragment layout (double-buffered) ----
#pragma unroll
    for (int q = 0; q < 4; ++q) {
      const int k = w * 16 + kg * 4 + q;
      sVc[(size_t)((k >> 5) * 64 + ((k >> 3) & 3) * 16 + c16) * 8 + (k & 7)]
          = (_Float16)va[q];
    }

    // ---- finale vq pairs from STAGED fp16 Q,V in sFc (pre-barrier reads) ----
    // element (p,row,col): off = p*4096 + (w*64 + ((col>>3)&3)*16 + row)*8 + (col&7)
    // lane cols = w*32 + c16*2 + {0,1}: one u32 covers both halves.
    uint32_t vqQ[4], vqV[4];
    {
      const size_t eb = (size_t)(w * 64 + (c16 >> 2) * 16 + kg * 4) * 8 + ((c16 * 2) & 7);
#pragma unroll
      for (int q = 0; q < 4; ++q) {
        vqQ[q] = *(const uint32_t*)(sFc + eb + (size_t)q * 8);            // plane 0 (Q)
        vqV[q] = *(const uint32_t*)(sFc + 2 * 4096 + eb + (size_t)q * 8); // plane 2 (V)
      }
    }

    // ---- next-tile staging write (waits vmcnt; covered by proj+softmax) ----
    if (more) write_stage(sFn);

    LDS_BARRIER();   // the ONLY barrier per tile

    // ---- W_o: A = sVc (LDS), B held; tiles nto = 2w, 2w+1 ----
    f32x4 accO[2] = {};
#pragma unroll
    for (int ks = 0; ks < 4; ++ks) {
      const f16x8 af = *(const f16x8*)(sVc + (size_t)(ks * 64 + lane) * 8);
      accO[0] = __builtin_amdgcn_mfma_f32_16x16x32_f16(af, bo[ks],     accO[0], 0, 0, 0);
      accO[1] = __builtin_amdgcn_mfma_f32_16x16x32_f16(af, bo[4 + ks], accO[1], 0, 0, 0);
    }

    // ---- final: out = silu((V*Q) * V_att_out); vq from staged fp16 ----
    const size_t row0 = ((size_t)blockIdx.x * TPB + t) * BM;
#pragma unroll
    for (int q = 0; q < 4; ++q) {
      const f16x2 aq = __builtin_bit_cast(f16x2, vqQ[q]);
      const f16x2 av = __builtin_bit_cast(f16x2, vqV[q]);
      const float att0 = (float)aq[0] * (float)av[0] * accO[0][q];
      const float att1 = (float)aq[1] * (float)av[1] * accO[1][q];
      float2 o;
      o.x = att0 / (1.f + __expf(-att0));
      o.y = att1 / (1.f + __expf(-att1));
      const size_t gb = (row0 + kg * 4 + q) * DIM + w * 32 + c16 * 2;
      *(float2*)(outg + gb) = o;
    }
  }
}

// ---------------------------------------------------------------------------
extern "C" void kernel_launch(void* const* d_in, const int* in_sizes, int n_in,
                              void* d_out, int out_size, void* d_ws, size_t ws_size,
                              hipStream_t stream) {
  const float* Q  = (const float*)d_in[0];
  const float* K  = (const float*)d_in[1];
  const float* V  = (const float*)d_in[2];
  const float* Wq = (const float*)d_in[3];
  const float* Wk = (const float*)d_in[4];
  const float* Wv = (const float*)d_in[5];
  const float* Wo = (const float*)d_in[6];
  const float* Wl = (const float*)d_in[7];
  const float* bl = (const float*)d_in[8];
  const float* Ws = (const float*)d_in[9];
  const float* bs = (const float*)d_in[10];
  _Float16* wt = (_Float16*)d_ws;   // 131072 halves = 256 KB of scratch
  float* out = (float*)d_out;

  pack_w<<<512, 256, 0, stream>>>(Wq, Wk, Wv, Wo, wt);
  uan_main<<<NBLK, 512, 0, stream>>>(Q, K, V, wt, Wl, bl, Ws, bs, out);
}

// Round 11
// 130.888 us; speedup vs baseline: 1.1647x; 1.0315x over previous
//
#include <hip/hip_runtime.h>
#include <hip/hip_fp16.h>
#include <stdint.h>

// Problem constants (hardcoded per reference)
#define NROWS 131072   // B*L
#define DIM   256      // D
#define HDK   128      // H*DK
#define BM    16       // rows per tile
#define TPB   16       // tiles per block
#define NBLK  (NROWS / BM / TPB)   // 512 blocks = 256 CUs x 2 resident

typedef _Float16 f16x8 __attribute__((ext_vector_type(8)));
typedef _Float16 f16x2 __attribute__((ext_vector_type(2)));
typedef float    f32x4 __attribute__((ext_vector_type(4)));

// LDS-ordering barrier WITHOUT the __syncthreads vmcnt(0) drain.
#define LDS_BARRIER() asm volatile("s_waitcnt lgkmcnt(0)\ns_barrier" ::: "memory")

// ---------------------------------------------------------------------------
// Pack W_q, W_k, W_v (256x128) and W_o (128x256) into fragment-linear fp16.
// Proj p at p*32768: frag idx = ((nt*8 + ks)*64 + lane)*8 + j,
//   value = W[ks*32 + (lane>>4)*8 + j][nt*16 + (lane&15)]   (nt = head)
// W_o at 98304: frag idx = ((nto*4 + ks)*64 + lane)*8 + j, COLUMN PERMUTE:
//   actual col n = (nto>>1)*32 + (lane&15)*2 + (nto&1)
// ---------------------------------------------------------------------------
__global__ void pack_w(const float* __restrict__ Wq, const float* __restrict__ Wk,
                       const float* __restrict__ Wv, const float* __restrict__ Wo,
                       _Float16* __restrict__ wt) {
  int t = blockIdx.x * 256 + threadIdx.x;   // 0 .. 131071
  int seg = t >> 15;                        // 0..3
  int i = t & 32767;
  int j = i & 7;
  int l = (i >> 3) & 63;
  int rest = i >> 9;                        // nt*KS + ks
  const float* W;
  int N, k, n;
  if (seg < 3) {
    W = (seg == 0) ? Wq : ((seg == 1) ? Wk : Wv);
    N = HDK;
    int ks = rest & 7, nt = rest >> 3;
    k = ks * 32 + ((l >> 4) << 3) + j;      // 0..255
    n = nt * 16 + (l & 15);                 // 0..127
  } else {
    W = Wo;
    N = DIM;
    int ks = rest & 3, nt = rest >> 2;      // nt = nto in 0..15
    k = ks * 32 + ((l >> 4) << 3) + j;      // 0..127
    n = ((nt >> 1) << 5) + ((l & 15) << 1) + (nt & 1);  // permuted column
  }
  wt[t] = (_Float16)W[k * N + n];
}

// ---------------------------------------------------------------------------
// v11 = v10 + cross-barrier software pipeline:
//  - W_o(t-1)+finale(t-1) retire in the SAME inter-barrier region as
//    proj(t)+softmax(t).  sVA double-buffer makes this hazard-free with ONE
//    barrier per tile.  vq regs read in region t, consumed in region t+1.
//  - staging vmcnt-drain (write_stage) at region END: each load's latency
//    cover = proj+softmax+W_o+finale (~5k cy), and waves bank a full tile
//    of retire work before stalling -> convoy cost amortized.
// Hazard audit: sF[t&1] read (proj,vq) region t, next write region t+1
// (tile t+2, after barrier t) OK.  sVA[x] write region x, read region x+1 OK.
// ---------------------------------------------------------------------------
__launch_bounds__(512, 2)
__global__ void uan_main(const float* __restrict__ Qg, const float* __restrict__ Kg,
                         const float* __restrict__ Vg, const _Float16* __restrict__ wt,
                         const float* __restrict__ Wl, const float* __restrict__ blv,
                         const float* __restrict__ Wsv, const float* __restrict__ bsv,
                         float* __restrict__ outg) {
  __shared__ __align__(16) _Float16 sF0[1536 * 8];   // 24576 B
  __shared__ __align__(16) _Float16 sF1[1536 * 8];   // 24576 B
  __shared__ __align__(16) _Float16 sVA0[256 * 8];   //  4096 B
  __shared__ __align__(16) _Float16 sVA1[256 * 8];   //  4096 B

  const int tid  = threadIdx.x;
  const int lane = tid & 63;
  const int w    = tid >> 6;        // wave 0..7 == head
  const int c16  = lane & 15;
  const int kg   = lane >> 4;

  // ---- held B-fragments (loaded once; compiler may re-load, acceptable) ----
  f16x8 bwp[24];   // proj: [p*8 + ks], head w
#pragma unroll
  for (int p = 0; p < 3; ++p)
#pragma unroll
    for (int ks = 0; ks < 8; ++ks)
      bwp[p * 8 + ks] = *(const f16x8*)(wt + p * 32768 +
                         (size_t)(((w * 8 + ks) * 64) + lane) * 8);
  f16x8 bo[8];     // W_o: [nt*4 + ks], tiles nto = 2w, 2w+1
#pragma unroll
  for (int nt = 0; nt < 2; ++nt)
#pragma unroll
    for (int ks = 0; ks < 4; ++ks)
      bo[nt * 4 + ks] = *(const f16x8*)(wt + 98304 +
                         (size_t)((((2 * w + nt) * 4 + ks) * 64) + lane) * 8);

  const float bl0 = blv[0], bl1 = blv[1], bs0 = bsv[0];
  // per-register softmax constants: hd = kg*4 + q
  float wl0q[4], wl1q[4], wsq[4];
#pragma unroll
  for (int q = 0; q < 4; ++q) {
    wl0q[q] = Wl[kg * 4 + q];
    wl1q[q] = Wl[16 + kg * 4 + q];
    wsq[q]  = Wsv[kg * 4 + q];
  }

  // staging: thread stages row (row0+c16)'s cols [w*32+kg*8, +8) of each plane
  const size_t soff  = (size_t)c16 * DIM + w * 32 + kg * 8;
  const size_t sfrag = (size_t)(w * 64 + lane) * 8;   // + p*4096 per plane

  float4 sa[3][2];
  auto issue_stage = [&](int t) {
    const size_t row0 = ((size_t)blockIdx.x * TPB + t) * BM;
#pragma unroll
    for (int p = 0; p < 3; ++p) {
      const float* base = (p == 0) ? Qg : ((p == 1) ? Kg : Vg);
      const float* src  = base + row0 * DIM + soff;
      sa[p][0] = *(const float4*)src;
      sa[p][1] = *(const float4*)(src + 4);
    }
  };
  auto write_stage = [&](_Float16* sFn) {
#pragma unroll
    for (int p = 0; p < 3; ++p) {
      f16x8 h;
      h[0] = (_Float16)sa[p][0].x; h[1] = (_Float16)sa[p][0].y;
      h[2] = (_Float16)sa[p][0].z; h[3] = (_Float16)sa[p][0].w;
      h[4] = (_Float16)sa[p][1].x; h[5] = (_Float16)sa[p][1].y;
      h[6] = (_Float16)sa[p][1].z; h[7] = (_Float16)sa[p][1].w;
      *(f16x8*)(sFn + p * 4096 + sfrag) = h;
    }
  };

  // retire phase: W_o MFMA from sVA + SiLU finale with carried vq regs
  auto wo_finale = [&](const _Float16* sVp, const uint32_t* vq0, const uint32_t* vq2, int tt) {
    f32x4 accO[2] = {};
#pragma unroll
    for (int ks = 0; ks < 4; ++ks) {
      const f16x8 af = *(const f16x8*)(sVp + (size_t)(ks * 64 + lane) * 8);
      accO[0] = __builtin_amdgcn_mfma_f32_16x16x32_f16(af, bo[ks],     accO[0], 0, 0, 0);
      accO[1] = __builtin_amdgcn_mfma_f32_16x16x32_f16(af, bo[4 + ks], accO[1], 0, 0, 0);
    }
    const size_t row0 = ((size_t)blockIdx.x * TPB + tt) * BM;
#pragma unroll
    for (int q = 0; q < 4; ++q) {
      const f16x2 aq = __builtin_bit_cast(f16x2, vq0[q]);
      const f16x2 av = __builtin_bit_cast(f16x2, vq2[q]);
      const float att0 = (float)aq[0] * (float)av[0] * accO[0][q];
      const float att1 = (float)aq[1] * (float)av[1] * accO[1][q];
      float2 o;
      o.x = att0 / (1.f + __expf(-att0));
      o.y = att1 / (1.f + __expf(-att1));
      const size_t gb = (row0 + kg * 4 + q) * DIM + w * 32 + c16 * 2;
      *(float2*)(outg + gb) = o;
    }
  };

  // carried finale operands (read region t, consumed region t+1)
  uint32_t cvqQ[4], cvqV[4];

  // prologue: stage tile 0
  issue_stage(0);
  write_stage(sF0);
  LDS_BARRIER();

  for (int t = 0; t < TPB; ++t) {
    _Float16* sFc = (t & 1) ? sF1 : sF0;
    _Float16* sFn = (t & 1) ? sF0 : sF1;
    _Float16* sVc = (t & 1) ? sVA1 : sVA0;
    _Float16* sVp = (t & 1) ? sVA0 : sVA1;
    const bool more = (t + 1 < TPB);
    if (more) issue_stage(t + 1);        // next-tile global loads in flight

    // ---- projections, swapped operands: accP holds P^T (row=c16, hd=kg*4+q) ----
    f32x4 accP[3] = {};
#pragma unroll
    for (int p = 0; p < 3; ++p)
#pragma unroll
      for (int ks = 0; ks < 8; ++ks) {
        const f16x8 af = *(const f16x8*)(sFc + (size_t)(((p * 8 + ks) * 64) + lane) * 8);
        accP[p] = __builtin_amdgcn_mfma_f32_16x16x32_f16(bwp[p * 8 + ks], af, accP[p], 0, 0, 0);
      }

    // ---- gated softmax: head-dim is register axis; reduce = 3 adds + 2 shfl ----
    float va[4];
    {
      float left[4], right[4];
      float pd0 = 0.f, pd1 = 0.f;
#pragma unroll
      for (int q = 0; q < 4; ++q) {
        const float qh = accP[0][q], kh = accP[1][q], vh = accP[2][q];
        left[q]  = kh * qh;
        right[q] = vh * qh;
        pd0 += left[q] * wl0q[q];
        pd1 += left[q] * wl1q[q];
      }
      pd0 += __shfl_xor(pd0, 16); pd0 += __shfl_xor(pd0, 32);
      pd1 += __shfl_xor(pd1, 16); pd1 += __shfl_xor(pd1, 32);
      const float m0 = 1.f / (1.f + __expf(-(pd0 + bl0)));
      const float m1 = 1.f / (1.f + __expf(-(pd1 + bl1)));
      const float mm = m0 * m1;
      float pnum = 0.f, pden = 0.f;
      float ev[4];
#pragma unroll
      for (int q = 0; q < 4; ++q) {
        ev[q] = __expf(left[q] * mm);    // |arg| <~ 40: f32-safe without max-sub
        pnum += ev[q] * wsq[q];
        pden += ev[q];
      }
      pnum += __shfl_xor(pnum, 16); pnum += __shfl_xor(pnum, 32);
      pden += __shfl_xor(pden, 16); pden += __shfl_xor(pden, 32);
      const float score = pnum / pden + bs0;
#pragma unroll
      for (int q = 0; q < 4; ++q) va[q] = score * right[q];
    }

    // ---- store V_att^T values into W_o A-fragment layout (double-buffered) ----
#pragma unroll
    for (int q = 0; q < 4; ++q) {
      const int k = w * 16 + kg * 4 + q;
      sVc[(size_t)((k >> 5) * 64 + ((k >> 3) & 3) * 16 + c16) * 8 + (k & 7)]
          = (_Float16)va[q];
    }

    // ---- read this tile's finale vq pairs from staged fp16 Q,V in sFc ----
    uint32_t nvqQ[4], nvqV[4];
    {
      const size_t eb = (size_t)(w * 64 + (c16 >> 2) * 16 + kg * 4) * 8 + ((c16 * 2) & 7);
#pragma unroll
      for (int q = 0; q < 4; ++q) {
        nvqQ[q] = *(const uint32_t*)(sFc + eb + (size_t)q * 8);            // plane 0 (Q)
        nvqV[q] = *(const uint32_t*)(sFc + 2 * 4096 + eb + (size_t)q * 8); // plane 2 (V)
      }
    }

    // ---- retire previous tile: W_o(t-1) + finale(t-1) (independent work) ----
    if (t > 0) wo_finale(sVp, cvqQ, cvqV, t - 1);
#pragma unroll
    for (int q = 0; q < 4; ++q) { cvqQ[q] = nvqQ[q]; cvqV[q] = nvqV[q]; }

    // ---- next-tile staging write (vmcnt drain at region END, max cover) ----
    if (more) write_stage(sFn);

    LDS_BARRIER();   // the ONLY barrier per tile
  }

  // epilogue: retire the last tile
  wo_finale((TPB & 1) ? sVA0 : sVA1, cvqQ, cvqV, TPB - 1);
}

// ---------------------------------------------------------------------------
extern "C" void kernel_launch(void* const* d_in, const int* in_sizes, int n_in,
                              void* d_out, int out_size, void* d_ws, size_t ws_size,
                              hipStream_t stream) {
  const float* Q  = (const float*)d_in[0];
  const float* K  = (const float*)d_in[1];
  const float* V  = (const float*)d_in[2];
  const float* Wq = (const float*)d_in[3];
  const float* Wk = (const float*)d_in[4];
  const float* Wv = (const float*)d_in[5];
  const float* Wo = (const float*)d_in[6];
  const float* Wl = (const float*)d_in[7];
  const float* bl = (const float*)d_in[8];
  const float* Ws = (const float*)d_in[9];
  const float* bs = (const float*)d_in[10];
  _Float16* wt = (_Float16*)d_ws;   // 131072 halves = 256 KB of scratch
  float* out = (float*)d_out;

  pack_w<<<512, 256, 0, stream>>>(Wq, Wk, Wv, Wo, wt);
  uan_main<<<NBLK, 512, 0, stream>>>(Q, K, V, wt, Wl, bl, Ws, bs, out);
}